// Round 1
// baseline (323.945 us; speedup 1.0000x reference)
//
#include <hip/hip_runtime.h>
#include <hip/hip_bf16.h>

#define EPS 1e-5f

// ---------- bf16 helpers (RNE) ----------
__device__ __forceinline__ unsigned short f2bf(float f) {
    unsigned int u = __builtin_bit_cast(unsigned int, f);
    unsigned int r = u + 0x7FFFu + ((u >> 16) & 1u);
    return (unsigned short)(r >> 16);
}
__device__ __forceinline__ float bf2f(unsigned short b) {
    unsigned int u = ((unsigned int)b) << 16;
    return __builtin_bit_cast(float, u);
}

typedef __attribute__((ext_vector_type(8))) short short8;   // 8 bf16 (4 VGPRs)
typedef __attribute__((ext_vector_type(4))) float floatx4;  // MFMA accumulator

// =====================================================================
// Kernel A: y = relu(bn(conv1x1(x)))  -> bf16 workspace
// GEMM: M=256 (o), K=256 (c), N=10240 per batch (p=h*160+w)
// Tile 128x128, BK=32 (one 16x16x32 MFMA spans full BK), 4 waves 2x2.
// =====================================================================
#define BM 128
#define BN 128
#define BK 32
#define SK 40   // LDS row stride (bf16 elts): 80B rows -> 16B-aligned b128, 2-way banks (free)

__global__ __launch_bounds__(256) void conv1x1_bn_relu(
    const float* __restrict__ x,       // [8][256][10240]
    const float* __restrict__ w,       // [256][256]  w[o][c]
    const float* __restrict__ cb,
    const float* __restrict__ gamma, const float* __restrict__ beta,
    const float* __restrict__ mean,  const float* __restrict__ var,
    unsigned short* __restrict__ y)    // bf16 [8][256][10240]
{
    const int nt  = blockIdx.x;   // 0..79  pixel tile
    const int mb  = blockIdx.y;   // 0..1   channel tile
    const int b   = blockIdx.z;   // 0..7
    const int tid = threadIdx.x;

    __shared__ unsigned short Al[BM * SK]; // [m][k]
    __shared__ unsigned short Bl[BN * SK]; // [n][k]  (transposed stage)
    __shared__ float s1[BM], u1[BM];

    const int m0 = mb * BM;
    const int p0 = nt * BN;

    if (tid < BM) {
        int o = m0 + tid;
        float s = gamma[o] * rsqrtf(var[o] + EPS);
        s1[tid] = s;
        u1[tid] = cb[o] * s + beta[o] - mean[o] * s;
    }

    const float* xb = x + (size_t)b * 256 * 10240;

    floatx4 acc[4][4];
#pragma unroll
    for (int i = 0; i < 4; i++)
#pragma unroll
        for (int j = 0; j < 4; j++) acc[i][j] = (floatx4)0.0f;

    const int lane = tid & 63;
    const int wv   = tid >> 6;
    const int wm   = (wv & 1) * 64;
    const int wn   = (wv >> 1) * 64;
    const int lm   = lane & 15;
    const int lq   = lane >> 4;

    const int nB = tid & 127;          // B-stage: this thread's n
    const int kB = (tid >> 7) * 4;     // B-stage: k group base (0 or 4)

    for (int k0 = 0; k0 < 256; k0 += BK) {
        __syncthreads();
        // ---- stage A: W[m0+m][k0..k0+31] fp32 -> bf16 LDS [m][k]
        {
            int id = tid;
#pragma unroll
            for (int it = 0; it < 4; it++, id += 256) {
                int m  = id >> 3;      // 0..127
                int f4 = id & 7;       // 0..7
                float4 v = *reinterpret_cast<const float4*>(
                    w + (size_t)(m0 + m) * 256 + k0 + f4 * 4);
                *reinterpret_cast<ushort4*>(&Al[m * SK + f4 * 4]) =
                    make_ushort4(f2bf(v.x), f2bf(v.y), f2bf(v.z), f2bf(v.w));
            }
        }
        // ---- stage B transposed: x[k][p0+n] -> LDS [n][k]
        {
            int kb = kB;
#pragma unroll
            for (int it = 0; it < 4; it++, kb += 8) {
                float v0 = xb[(size_t)(k0 + kb + 0) * 10240 + p0 + nB];
                float v1 = xb[(size_t)(k0 + kb + 1) * 10240 + p0 + nB];
                float v2 = xb[(size_t)(k0 + kb + 2) * 10240 + p0 + nB];
                float v3 = xb[(size_t)(k0 + kb + 3) * 10240 + p0 + nB];
                *reinterpret_cast<ushort4*>(&Bl[nB * SK + kb]) =
                    make_ushort4(f2bf(v0), f2bf(v1), f2bf(v2), f2bf(v3));
            }
        }
        __syncthreads();

        // ---- fragments + MFMA
        short8 af[4], bfr[4];
#pragma unroll
        for (int i = 0; i < 4; i++) {
            int m = wm + i * 16 + lm;
            af[i] = *reinterpret_cast<const short8*>(&Al[m * SK + lq * 8]);
        }
#pragma unroll
        for (int j = 0; j < 4; j++) {
            int n = wn + j * 16 + lm;
            bfr[j] = *reinterpret_cast<const short8*>(&Bl[n * SK + lq * 8]);
        }
#pragma unroll
        for (int i = 0; i < 4; i++)
#pragma unroll
            for (int j = 0; j < 4; j++)
                acc[i][j] = __builtin_amdgcn_mfma_f32_16x16x32_bf16(
                    af[i], bfr[j], acc[i][j], 0, 0, 0);
    }

    // ---- epilogue: BN+ReLU, store bf16
    unsigned short* yb = y + (size_t)b * 256 * 10240;
#pragma unroll
    for (int i = 0; i < 4; i++) {
        int mo_base = wm + i * 16 + lq * 4;     // D row = (lane>>4)*4 + r
#pragma unroll
        for (int j = 0; j < 4; j++) {
            int p = p0 + wn + j * 16 + lm;      // D col = lane&15
#pragma unroll
            for (int r = 0; r < 4; r++) {
                int mo = mo_base + r;
                float v = acc[i][j][r] * s1[mo] + u1[mo];
                v = fmaxf(v, 0.0f);
                yb[(size_t)(m0 + mo) * 10240 + p] = f2bf(v);
            }
        }
    }
}

// =====================================================================
// Kernel B: out = x + SCALE * sum_s wt_s * relu(bn(dwconv3x3(roll(y,s))))
// Per (b,c): 64x160 plane, 32x40 tiles. y tile + halo(4) in LDS (circular),
// z_circ = circular dwconv3x3(y) over tile+3; interior = 12 z lookups,
// border (h in {0,63} or w in {0,159}) = masked 9-tap per shift.
// =====================================================================
__global__ __launch_bounds__(256) void refine_accum(
    const float* __restrict__ x,
    const unsigned short* __restrict__ y,  // bf16
    const float* __restrict__ rw,          // [256][9]
    const float* __restrict__ rb,
    const float* __restrict__ rg, const float* __restrict__ rbe,
    const float* __restrict__ rm, const float* __restrict__ rv,
    float* __restrict__ out)
{
    const int bi   = blockIdx.x;
    const int tile = bi & 7;
    const int c    = (bi >> 3) & 255;
    const int b    = bi >> 11;
    const int th0  = (tile >> 2) * 32;
    const int tw0  = (tile & 3) * 40;
    const int tid  = threadIdx.x;

    __shared__ float yt[40 * 49];  // rows [th0-4, th0+36), cols [tw0-4, tw0+44), stride 49
    __shared__ float zt[38 * 47];  // rows [th0-3, th0+35), cols [tw0-3, tw0+43), stride 47

    const size_t img = ((size_t)b * 256 + c) * 10240;
    const unsigned short* yp = y + img;

    float w9[9];
#pragma unroll
    for (int t = 0; t < 9; t++) w9[t] = rw[c * 9 + t];
    const float s2 = rg[c] * rsqrtf(rv[c] + EPS);
    const float u2 = rb[c] * s2 + rbe[c] - rm[c] * s2;

    // ---- load y tile + halo with circular wrap (roll semantics)
    for (int id = tid; id < 40 * 48; id += 256) {
        int r  = id / 48, cc = id - r * 48;
        int gh = th0 - 4 + r;  if (gh < 0) gh += 64;  else if (gh >= 64) gh -= 64;
        int gw = tw0 - 4 + cc; if (gw < 0) gw += 160; else if (gw >= 160) gw -= 160;
        yt[r * 49 + cc] = bf2f(yp[gh * 160 + gw]);
    }
    __syncthreads();

    // ---- z_circ tile (38 x 46): z(r,cc) centered at yt(r+1, cc+1)
    for (int id = tid; id < 38 * 46; id += 256) {
        int r = id / 46, cc = id - r * 46;
        float a = 0.f;
#pragma unroll
        for (int dh = 0; dh < 3; dh++)
#pragma unroll
            for (int dw = 0; dw < 3; dw++)
                a += w9[dh * 3 + dw] * yt[(r + dh) * 49 + (cc + dw)];
        zt[r * 47 + cc] = a;
    }
    __syncthreads();

    const float w1 = 0.80073740f, w2 = 0.41111229f, w3 = 0.13533528f;
    const float SCALE = 0.5f / (4.f * (w1 + w2 + w3));
    const int   SH[12] = {1, 2, 3, -1, -2, -3, 0, 0, 0, 0, 0, 0};
    const int   SW[12] = {0, 0, 0, 0, 0, 0, -1, -2, -3, 1, 2, 3};
    const float WT[12] = {w1, w2, w3, w1, w2, w3, w1, w2, w3, w1, w2, w3};

    for (int id = tid; id < 32 * 40; id += 256) {
        int oh = id / 40, ow = id - oh * 40;
        int h = th0 + oh, w = tw0 + ow;
        size_t gidx = img + h * 160 + w;
        float accv = 0.f;
        if (h >= 1 && h <= 62 && w >= 1 && w <= 158) {
            // interior: dwconv(roll(y,s))[h,w] == z_circ[h-sh, w-sw]
#pragma unroll
            for (int s = 0; s < 12; s++) {
                float zv = zt[(oh + 3 - SH[s]) * 47 + (ow + 3 - SW[s])];
                accv += WT[s] * fmaxf(zv * s2 + u2, 0.f);
            }
        } else {
            // border: zero-padding masks taps by OUTPUT position (shift-independent)
            float mw[9];
#pragma unroll
            for (int dh = 0; dh < 3; dh++)
#pragma unroll
                for (int dw = 0; dw < 3; dw++) {
                    int ih = h + dh - 1, iw = w + dw - 1;
                    mw[dh * 3 + dw] =
                        (ih >= 0 && ih < 64 && iw >= 0 && iw < 160) ? w9[dh * 3 + dw] : 0.f;
                }
#pragma unroll
            for (int s = 0; s < 12; s++) {
                float v = 0.f;
#pragma unroll
                for (int dh = 0; dh < 3; dh++)
#pragma unroll
                    for (int dw = 0; dw < 3; dw++)
                        v += mw[dh * 3 + dw] *
                             yt[(oh + 3 - SH[s] + dh) * 49 + (ow + 3 - SW[s] + dw)];
                accv += WT[s] * fmaxf(v * s2 + u2, 0.f);
            }
        }
        out[gidx] = x[gidx] + SCALE * accv;
    }
}

extern "C" void kernel_launch(void* const* d_in, const int* in_sizes, int n_in,
                              void* d_out, int out_size, void* d_ws, size_t ws_size,
                              hipStream_t stream) {
    const float* x      = (const float*)d_in[0];
    const float* conv_w = (const float*)d_in[1];
    const float* conv_b = (const float*)d_in[2];
    const float* bn_g   = (const float*)d_in[3];
    const float* bn_b   = (const float*)d_in[4];
    const float* bn_m   = (const float*)d_in[5];
    const float* bn_v   = (const float*)d_in[6];
    const float* ref_w  = (const float*)d_in[7];
    const float* ref_b  = (const float*)d_in[8];
    const float* rbn_g  = (const float*)d_in[9];
    const float* rbn_b  = (const float*)d_in[10];
    const float* rbn_m  = (const float*)d_in[11];
    const float* rbn_v  = (const float*)d_in[12];
    float* out          = (float*)d_out;
    unsigned short* y_ws = (unsigned short*)d_ws;  // bf16 y: 8*256*10240*2 = 41.9 MB

    conv1x1_bn_relu<<<dim3(80, 2, 8), 256, 0, stream>>>(
        x, conv_w, conv_b, bn_g, bn_b, bn_m, bn_v, y_ws);
    refine_accum<<<dim3(8 * 256 * 8), 256, 0, stream>>>(
        x, y_ws, ref_w, ref_b, rbn_g, rbn_b, rbn_m, rbn_v, out);
}

// Round 2
// 254.280 us; speedup vs baseline: 1.2740x; 1.2740x over previous
//
#include <hip/hip_runtime.h>
#include <hip/hip_bf16.h>

#define EPS 1e-5f

// ---------- bf16 helpers (RNE) ----------
__device__ __forceinline__ unsigned short f2bf(float f) {
    unsigned int u = __builtin_bit_cast(unsigned int, f);
    unsigned int r = u + 0x7FFFu + ((u >> 16) & 1u);
    return (unsigned short)(r >> 16);
}
__device__ __forceinline__ float bf2f(unsigned short b) {
    unsigned int u = ((unsigned int)b) << 16;
    return __builtin_bit_cast(float, u);
}

typedef __attribute__((ext_vector_type(8))) short short8;   // 8 bf16 (4 VGPRs)
typedef __attribute__((ext_vector_type(4))) float floatx4;  // MFMA accumulator

// =====================================================================
// Kernel A: y = relu(bn(conv1x1(x)))  -> bf16 workspace
// (unchanged structure; grid swizzled so mb=0/1 of same pixel tile are
//  adjacent in dispatch -> x tile stays L2-hot for the second read)
// =====================================================================
#define BM 128
#define BN 128
#define BK 32
#define SK 40

__global__ __launch_bounds__(256) void conv1x1_bn_relu(
    const float* __restrict__ x,
    const float* __restrict__ w,
    const float* __restrict__ cb,
    const float* __restrict__ gamma, const float* __restrict__ beta,
    const float* __restrict__ mean,  const float* __restrict__ var,
    unsigned short* __restrict__ y)
{
    const int nt  = blockIdx.x >> 1;   // pixel tile 0..79
    const int mb  = blockIdx.x & 1;    // channel tile (adjacent for L2 reuse)
    const int b   = blockIdx.z;
    const int tid = threadIdx.x;

    __shared__ unsigned short Al[BM * SK];
    __shared__ unsigned short Bl[BN * SK];
    __shared__ float s1[BM], u1[BM];

    const int m0 = mb * BM;
    const int p0 = nt * BN;

    if (tid < BM) {
        int o = m0 + tid;
        float s = gamma[o] * rsqrtf(var[o] + EPS);
        s1[tid] = s;
        u1[tid] = cb[o] * s + beta[o] - mean[o] * s;
    }

    const float* xb = x + (size_t)b * 256 * 10240;

    floatx4 acc[4][4];
#pragma unroll
    for (int i = 0; i < 4; i++)
#pragma unroll
        for (int j = 0; j < 4; j++) acc[i][j] = (floatx4)0.0f;

    const int lane = tid & 63;
    const int wv   = tid >> 6;
    const int wm   = (wv & 1) * 64;
    const int wn   = (wv >> 1) * 64;
    const int lm   = lane & 15;
    const int lq   = lane >> 4;

    const int nB = tid & 127;
    const int kB = (tid >> 7) * 4;

    for (int k0 = 0; k0 < 256; k0 += BK) {
        __syncthreads();
        {
            int id = tid;
#pragma unroll
            for (int it = 0; it < 4; it++, id += 256) {
                int m  = id >> 3;
                int f4 = id & 7;
                float4 v = *reinterpret_cast<const float4*>(
                    w + (size_t)(m0 + m) * 256 + k0 + f4 * 4);
                *reinterpret_cast<ushort4*>(&Al[m * SK + f4 * 4]) =
                    make_ushort4(f2bf(v.x), f2bf(v.y), f2bf(v.z), f2bf(v.w));
            }
        }
        {
            int kb = kB;
#pragma unroll
            for (int it = 0; it < 4; it++, kb += 8) {
                float v0 = xb[(size_t)(k0 + kb + 0) * 10240 + p0 + nB];
                float v1 = xb[(size_t)(k0 + kb + 1) * 10240 + p0 + nB];
                float v2 = xb[(size_t)(k0 + kb + 2) * 10240 + p0 + nB];
                float v3 = xb[(size_t)(k0 + kb + 3) * 10240 + p0 + nB];
                *reinterpret_cast<ushort4*>(&Bl[nB * SK + kb]) =
                    make_ushort4(f2bf(v0), f2bf(v1), f2bf(v2), f2bf(v3));
            }
        }
        __syncthreads();

        short8 af[4], bfr[4];
#pragma unroll
        for (int i = 0; i < 4; i++) {
            int m = wm + i * 16 + lm;
            af[i] = *reinterpret_cast<const short8*>(&Al[m * SK + lq * 8]);
        }
#pragma unroll
        for (int j = 0; j < 4; j++) {
            int n = wn + j * 16 + lm;
            bfr[j] = *reinterpret_cast<const short8*>(&Bl[n * SK + lq * 8]);
        }
#pragma unroll
        for (int i = 0; i < 4; i++)
#pragma unroll
            for (int j = 0; j < 4; j++)
                acc[i][j] = __builtin_amdgcn_mfma_f32_16x16x32_bf16(
                    af[i], bfr[j], acc[i][j], 0, 0, 0);
    }

    unsigned short* yb = y + (size_t)b * 256 * 10240;
#pragma unroll
    for (int i = 0; i < 4; i++) {
        int mo_base = wm + i * 16 + lq * 4;
#pragma unroll
        for (int j = 0; j < 4; j++) {
            int p = p0 + wn + j * 16 + lm;
#pragma unroll
            for (int r = 0; r < 4; r++) {
                int mo = mo_base + r;
                float v = acc[i][j][r] * s1[mo] + u1[mo];
                v = fmaxf(v, 0.0f);
                yb[(size_t)(m0 + mo) * 10240 + p] = f2bf(v);
            }
        }
    }
}

// =====================================================================
// Kernel B (rewritten): per (b,c,strip40): full 64 rows x 40 cols.
//  1) yt: 64 x 50 fp32 (cols w=c0-5..c0+44, circular wrap at load; rows=h)
//  2) qt = relu(bn(circular 3x3 conv)) for 64 x 48 cols (vectorized x4)
//  3) interior formula EVERYWHERE (uniform, no divergence):
//     acc = sum_d wd*(q[(r-d)&63][c]+q[(r+d)&63][c]+q[r][c-d]+q[r][c+d])
//     stores predicated off at image-border pixels
//  4) tiny uniform border fixup (<=142 lanes) recomputes exact masked taps
// =====================================================================
#define YS 52   // yt row stride (floats), 208 B: 16B-aligned rows
#define QS 52   // qt row stride (floats)

__global__ __launch_bounds__(256) void refine_accum(
    const float* __restrict__ x,
    const unsigned short* __restrict__ y,
    const float* __restrict__ rw,
    const float* __restrict__ rb,
    const float* __restrict__ rg, const float* __restrict__ rbe,
    const float* __restrict__ rm, const float* __restrict__ rv,
    float* __restrict__ out)
{
    const int bi    = blockIdx.x;
    const int strip = bi & 3;
    const int c     = (bi >> 2) & 255;
    const int b     = bi >> 10;
    const int c0    = strip * 40;
    const int tid   = threadIdx.x;

    __shared__ float yt[64 * YS];   // col j <-> w = c0-5+j (mod 160), row = h
    __shared__ float qt[64 * QS];   // col qc <-> w = c0-4+qc, row = h

    const size_t img = ((size_t)b * 256 + c) * 10240;
    const unsigned short* yp = y + img;

    float w9[9];
#pragma unroll
    for (int t = 0; t < 9; t++) w9[t] = rw[c * 9 + t];
    const float s2 = rg[c] * rsqrtf(rv[c] + EPS);
    const float u2 = rb[c] * s2 + rbe[c] - rm[c] * s2;

    // ---- 1) load y tile: 64 rows x 50 cols, circular col wrap
    for (int id = tid; id < 64 * 50; id += 256) {
        int r = id / 50, j = id - r * 50;
        int gw = c0 - 5 + j;
        if (gw < 0) gw += 160; else if (gw >= 160) gw -= 160;
        yt[r * YS + j] = bf2f(yp[r * 160 + gw]);
    }
    __syncthreads();

    // ---- 2) q = relu(bn(z_circ)), 64 rows x 48 cols, 4 cols per task
    for (int t = tid; t < 64 * 12; t += 256) {
        int r = t / 12, g = t - r * 12;
        int q0 = 4 * g;                      // qc of first output
        int rm1 = (r + 63) & 63, rp1 = (r + 1) & 63;
        // taps for qc..qc+2 -> yt cols j = qc..qc+2; need j = q0 .. q0+5
        float A[8], B[8], C[8];
        *reinterpret_cast<float4*>(&A[0]) = *reinterpret_cast<const float4*>(&yt[rm1 * YS + q0]);
        *reinterpret_cast<float4*>(&A[4]) = *reinterpret_cast<const float4*>(&yt[rm1 * YS + q0 + 4]);
        *reinterpret_cast<float4*>(&B[0]) = *reinterpret_cast<const float4*>(&yt[r   * YS + q0]);
        *reinterpret_cast<float4*>(&B[4]) = *reinterpret_cast<const float4*>(&yt[r   * YS + q0 + 4]);
        *reinterpret_cast<float4*>(&C[0]) = *reinterpret_cast<const float4*>(&yt[rp1 * YS + q0]);
        *reinterpret_cast<float4*>(&C[4]) = *reinterpret_cast<const float4*>(&yt[rp1 * YS + q0 + 4]);
        float4 qv;
        float* qvp = reinterpret_cast<float*>(&qv);
#pragma unroll
        for (int i = 0; i < 4; i++) {
            float z = w9[0] * A[i] + w9[1] * A[i + 1] + w9[2] * A[i + 2]
                    + w9[3] * B[i] + w9[4] * B[i + 1] + w9[5] * B[i + 2]
                    + w9[6] * C[i] + w9[7] * C[i + 1] + w9[8] * C[i + 2];
            qvp[i] = fmaxf(z * s2 + u2, 0.0f);
        }
        *reinterpret_cast<float4*>(&qt[r * QS + q0]) = qv;
    }
    __syncthreads();

    const float w1 = 0.80073740f, w2 = 0.41111229f, w3 = 0.13533528f;
    const float SCALE = 0.5f / (4.0f * (w1 + w2 + w3));

    // ---- 3) interior formula, 4 outputs per task, uniform
    for (int t = tid; t < 64 * 10; t += 256) {
        int r = t / 10, g = t - r * 10;
        int qb = 4 * g + 4;                  // qc of output col w=c0+4g
        float vm1[4], vm2[4], vm3[4], vp1[4], vp2[4], vp3[4], H[12];
        *reinterpret_cast<float4*>(&vm1[0]) = *reinterpret_cast<const float4*>(&qt[((r + 63) & 63) * QS + qb]);
        *reinterpret_cast<float4*>(&vm2[0]) = *reinterpret_cast<const float4*>(&qt[((r + 62) & 63) * QS + qb]);
        *reinterpret_cast<float4*>(&vm3[0]) = *reinterpret_cast<const float4*>(&qt[((r + 61) & 63) * QS + qb]);
        *reinterpret_cast<float4*>(&vp1[0]) = *reinterpret_cast<const float4*>(&qt[((r + 1) & 63) * QS + qb]);
        *reinterpret_cast<float4*>(&vp2[0]) = *reinterpret_cast<const float4*>(&qt[((r + 2) & 63) * QS + qb]);
        *reinterpret_cast<float4*>(&vp3[0]) = *reinterpret_cast<const float4*>(&qt[((r + 3) & 63) * QS + qb]);
        *reinterpret_cast<float4*>(&H[0])  = *reinterpret_cast<const float4*>(&qt[r * QS + qb - 4]);
        *reinterpret_cast<float4*>(&H[4])  = *reinterpret_cast<const float4*>(&qt[r * QS + qb]);
        *reinterpret_cast<float4*>(&H[8])  = *reinterpret_cast<const float4*>(&qt[r * QS + qb + 4]);

        int h = r, w0 = c0 + 4 * g;
        size_t gidx = img + (size_t)h * 160 + w0;
        float4 xv = *reinterpret_cast<const float4*>(&x[gidx]);
        const float* xvp = reinterpret_cast<const float*>(&xv);
        float ov[4];
#pragma unroll
        for (int i = 0; i < 4; i++) {
            float vs = w1 * (vm1[i] + vp1[i]) + w2 * (vm2[i] + vp2[i]) + w3 * (vm3[i] + vp3[i]);
            float hs = w1 * (H[i + 3] + H[i + 5]) + w2 * (H[i + 2] + H[i + 6]) + w3 * (H[i + 1] + H[i + 7]);
            ov[i] = xvp[i] + SCALE * (vs + hs);
        }
        bool rowok = (h != 0) && (h != 63);
        if (rowok) {
            if (c0 == 0 && g == 0) {
                out[gidx + 1] = ov[1]; out[gidx + 2] = ov[2]; out[gidx + 3] = ov[3];
            } else if (c0 == 120 && g == 9) {
                out[gidx] = ov[0]; out[gidx + 1] = ov[1]; out[gidx + 2] = ov[2];
            } else {
                *reinterpret_cast<float4*>(&out[gidx]) =
                    make_float4(ov[0], ov[1], ov[2], ov[3]);
            }
        }
    }

    // ---- 4) border fixup: exact masked computation (uniform, tiny)
    const int SH[12] = {1, 2, 3, -1, -2, -3, 0, 0, 0, 0, 0, 0};
    const int SW[12] = {0, 0, 0, 0, 0, 0, -1, -2, -3, 1, 2, 3};
    const float WT[12] = {w1, w2, w3, w1, w2, w3, w1, w2, w3, w1, w2, w3};
    const bool edge = (c0 == 0) || (c0 == 120);
    const int nb = 80 + (edge ? 62 : 0);
    if (tid < nb) {
        int h, w;
        if (tid < 40)      { h = 0;  w = c0 + tid; }
        else if (tid < 80) { h = 63; w = c0 + tid - 40; }
        else               { h = tid - 79; w = (c0 == 0) ? 0 : 159; }
        float mw[9];
#pragma unroll
        for (int dh = 0; dh < 3; dh++)
#pragma unroll
            for (int dw = 0; dw < 3; dw++) {
                int ih = h + dh - 1, iw = w + dw - 1;
                mw[dh * 3 + dw] =
                    (ih >= 0 && ih < 64 && iw >= 0 && iw < 160) ? w9[dh * 3 + dw] : 0.0f;
            }
        float accv = 0.0f;
#pragma unroll
        for (int s = 0; s < 12; s++) {
            float conv = 0.0f;
#pragma unroll
            for (int dh = 0; dh < 3; dh++)
#pragma unroll
                for (int dw = 0; dw < 3; dw++) {
                    int row = (h + dh - 1 - SH[s]) & 63;
                    int jj  = (w - c0) + dw + 4 - SW[s];
                    conv += mw[dh * 3 + dw] * yt[row * YS + jj];
                }
            accv += WT[s] * fmaxf(conv * s2 + u2, 0.0f);
        }
        size_t gidx = img + (size_t)h * 160 + w;
        out[gidx] = x[gidx] + SCALE * accv;
    }
}

extern "C" void kernel_launch(void* const* d_in, const int* in_sizes, int n_in,
                              void* d_out, int out_size, void* d_ws, size_t ws_size,
                              hipStream_t stream) {
    const float* x      = (const float*)d_in[0];
    const float* conv_w = (const float*)d_in[1];
    const float* conv_b = (const float*)d_in[2];
    const float* bn_g   = (const float*)d_in[3];
    const float* bn_b   = (const float*)d_in[4];
    const float* bn_m   = (const float*)d_in[5];
    const float* bn_v   = (const float*)d_in[6];
    const float* ref_w  = (const float*)d_in[7];
    const float* ref_b  = (const float*)d_in[8];
    const float* rbn_g  = (const float*)d_in[9];
    const float* rbn_b  = (const float*)d_in[10];
    const float* rbn_m  = (const float*)d_in[11];
    const float* rbn_v  = (const float*)d_in[12];
    float* out          = (float*)d_out;
    unsigned short* y_ws = (unsigned short*)d_ws;  // bf16 y: 41.9 MB

    conv1x1_bn_relu<<<dim3(160, 1, 8), 256, 0, stream>>>(
        x, conv_w, conv_b, bn_g, bn_b, bn_m, bn_v, y_ws);
    refine_accum<<<dim3(8 * 256 * 4), 256, 0, stream>>>(
        x, y_ws, ref_w, ref_b, rbn_g, rbn_b, rbn_m, rbn_v, out);
}